// Round 2
// baseline (587.204 us; speedup 1.0000x reference)
//
#include <hip/hip_runtime.h>

// GCN 2-layer encoder on gfx950.
// Pipeline: hist(indeg) -> dinv -> exclusive scan (CSR row_ptr) -> scatter(col)
//           -> gemm1 -> aggregate(relu,+b1) -> gemm2 -> aggregate(+b2) -> d_out
// CSR-by-dst gather aggregation avoids 205M float atomics of the naive scatter.
// NOTE: harness passes ALL integer inputs as int32 (edge_index int64 in the
// reference arrives as const int*). Reading it as long long was R1's crash.

__global__ void init_cnt(int* __restrict__ cnt, int N) {
    int i = blockIdx.x * blockDim.x + threadIdx.x;
    if (i < N) cnt[i] = 0;
}

__global__ void hist(const int* __restrict__ dst, int* __restrict__ cnt, int E) {
    int e = blockIdx.x * blockDim.x + threadIdx.x;
    if (e < E) atomicAdd(&cnt[dst[e]], 1);
}

__global__ void compute_dinv(const int* __restrict__ cnt, float* __restrict__ dinv, int N) {
    int i = blockIdx.x * blockDim.x + threadIdx.x;
    if (i < N) dinv[i] = rsqrtf((float)(cnt[i] + 1));  // +1 self-loop; always > 0
}

// Per-block exclusive scan of cnt into rp; block totals into bsums. 1024 elems/block.
__global__ __launch_bounds__(1024) void scan1(const int* __restrict__ cnt, int* __restrict__ rp,
                                              int* __restrict__ bsums, int N) {
    __shared__ int s[1024];
    int tid = threadIdx.x;
    int gid = blockIdx.x * 1024 + tid;
    int v = (gid < N) ? cnt[gid] : 0;
    s[tid] = v;
    __syncthreads();
    for (int off = 1; off < 1024; off <<= 1) {
        int t = (tid >= off) ? s[tid - off] : 0;
        __syncthreads();
        s[tid] += t;
        __syncthreads();
    }
    if (gid < N) rp[gid] = s[tid] - v;  // exclusive
    if (tid == 1023) bsums[blockIdx.x] = s[1023];
}

// Exclusive scan of block sums (nb <= 256). Single block.
__global__ void scan2(int* __restrict__ bsums, int nb) {
    __shared__ int s[256];
    int tid = threadIdx.x;
    int v = (tid < nb) ? bsums[tid] : 0;
    s[tid] = v;
    __syncthreads();
    for (int off = 1; off < 256; off <<= 1) {
        int t = (tid >= off) ? s[tid - off] : 0;
        __syncthreads();
        s[tid] += t;
        __syncthreads();
    }
    if (tid < nb) bsums[tid] = s[tid] - v;
}

__global__ void scan3(int* __restrict__ rp, const int* __restrict__ bsums,
                      int* __restrict__ cursor, int N, int E) {
    int i = blockIdx.x * blockDim.x + threadIdx.x;
    if (i < N) {
        int r = rp[i] + bsums[i >> 10];
        rp[i] = r;
        cursor[i] = r;
    } else if (i == N) {
        rp[N] = E;
    }
}

__global__ void scatter(const int* __restrict__ src, const int* __restrict__ dst,
                        int* __restrict__ cursor, int* __restrict__ col, int E) {
    int e = blockIdx.x * blockDim.x + threadIdx.x;
    if (e < E) {
        int d = dst[e];
        int pos = atomicAdd(&cursor[d], 1);
        col[pos] = src[e];
    }
}

// H[N,COUT] = X[N,CIN] @ W[CIN,COUT]; W + R rows of X staged in LDS.
template <int CIN, int COUT>
__global__ void gemm(const float* __restrict__ X, const float* __restrict__ W,
                     float* __restrict__ H, int N) {
    constexpr int R = 256 / COUT;
    __shared__ float Ws[CIN * COUT];
    __shared__ float Xs[R * CIN];
    int tid = threadIdx.x;
    for (int i = tid; i < CIN * COUT; i += 256) Ws[i] = W[i];
    int rowBase = blockIdx.x * R;
    for (int i = tid; i < R * CIN; i += 256) {
        int gr = rowBase + i / CIN;
        Xs[i] = (gr < N) ? X[rowBase * CIN + i] : 0.f;
    }
    __syncthreads();
    int c = tid % COUT, r = tid / COUT;
    int row = rowBase + r;
    if (row >= N) return;
    float acc = 0.f;
#pragma unroll
    for (int k = 0; k < CIN; ++k) acc = fmaf(Xs[r * CIN + k], Ws[k * COUT + c], acc);
    H[row * COUT + c] = acc;
}

// out[i] = dinv[i] * ( h[i]*dinv[i] + sum_{e: dst=i} h[src_e]*dinv[src_e] ) + bias
// One wave per node (C=64) / half-wave (C=32); lane = channel -> coalesced gathers.
template <int C, bool RELU>
__global__ void aggregate(const float* __restrict__ h, const float* __restrict__ dinv,
                          const int* __restrict__ rp, const int* __restrict__ col,
                          const float* __restrict__ bias, float* __restrict__ out, int N) {
    int t = blockIdx.x * blockDim.x + threadIdx.x;
    int node = t / C;
    int c = t % C;
    if (node >= N) return;
    float dn = dinv[node];
    float acc = h[node * C + c] * dn;  // self-loop (inner factor)
    int e0 = rp[node], e1 = rp[node + 1];
    for (int e = e0; e < e1; ++e) {
        int s = col[e];
        acc = fmaf(h[s * C + c], dinv[s], acc);
    }
    float r = fmaf(acc, dn, bias[c]);
    if (RELU) r = fmaxf(r, 0.f);
    out[node * C + c] = r;
}

extern "C" void kernel_launch(void* const* d_in, const int* in_sizes, int n_in,
                              void* d_out, int out_size, void* d_ws, size_t ws_size,
                              hipStream_t stream) {
    const float* x = (const float*)d_in[0];
    const int* ei = (const int*)d_in[1];  // int64 in reference -> int32 from harness
    // d_in[2] = num_nodes scalar (unused; derived from in_sizes)
    const float* W1 = (const float*)d_in[3];
    const float* b1 = (const float*)d_in[4];
    const float* W2 = (const float*)d_in[5];
    const float* b2 = (const float*)d_in[6];

    constexpr int CIN = 64, CHID = 64, COUT = 32;
    const int N = in_sizes[0] / CIN;
    const int E = in_sizes[1] / 2;
    const int* src = ei;
    const int* dst = ei + E;

    // Carve workspace (~59 MB total). Everything is fully written before read;
    // harness re-poisons ws to 0xAA each launch, so no cross-call state.
    char* p = (char*)d_ws;
    auto carve = [&](size_t bytes) -> void* {
        void* q = (void*)p;
        p += (bytes + 255) & ~(size_t)255;
        return q;
    };
    int* cnt = (int*)carve((size_t)N * 4);      // indegree; reused as cursor
    int* rp = (int*)carve((size_t)(N + 1) * 4); // CSR row pointers
    int* bsums = (int*)carve(256 * 4);
    int* col = (int*)carve((size_t)E * 4);      // CSR column (src) indices
    float* dinv = (float*)carve((size_t)N * 4);
    float* h1 = (float*)carve((size_t)N * CHID * 4);
    float* agg1 = (float*)carve((size_t)N * CHID * 4);
    int* cursor = cnt;  // cnt dead after scan1
    float* h2 = h1;     // h1 dead after aggregate1

    const int gN = (N + 255) / 256;
    const int gE = (E + 255) / 256;
    const int nb = (N + 1023) / 1024;  // 98 for N=100000 (must be <= 256)

    init_cnt<<<gN, 256, 0, stream>>>(cnt, N);
    hist<<<gE, 256, 0, stream>>>(dst, cnt, E);
    compute_dinv<<<gN, 256, 0, stream>>>(cnt, dinv, N);
    scan1<<<nb, 1024, 0, stream>>>(cnt, rp, bsums, N);
    scan2<<<1, 256, 0, stream>>>(bsums, nb);
    scan3<<<(N + 1 + 255) / 256, 256, 0, stream>>>(rp, bsums, cursor, N, E);
    scatter<<<gE, 256, 0, stream>>>(src, dst, cursor, col, E);

    gemm<CIN, CHID><<<(N + 3) / 4, 256, 0, stream>>>(x, W1, h1, N);
    aggregate<CHID, true>
        <<<((size_t)N * CHID + 255) / 256, 256, 0, stream>>>(h1, dinv, rp, col, b1, agg1, N);
    gemm<CHID, COUT><<<(N + 7) / 8, 256, 0, stream>>>(agg1, W2, h2, N);
    aggregate<COUT, false>
        <<<((size_t)N * COUT + 255) / 256, 256, 0, stream>>>(h2, dinv, rp, col, b2, (float*)d_out, N);
}

// Round 3
// 446.579 us; speedup vs baseline: 1.3149x; 1.3149x over previous
//
#include <hip/hip_runtime.h>

// GCN 2-layer encoder on gfx950.
// Pipeline: memset(cnt) -> hist -> scan1(+dinv) -> scan2 -> scan3 -> scatter
//           -> gemm1*dinv -> aggregate4(relu,+b1) -> gemm2*dinv -> aggregate4(+b2)
// R3: latency-bound aggregate fixed via float4 gathers (4/8 independent
// node-walks per wave) + 4-way edge unroll (<=16 gathers in flight) + dinv
// row-scale folded into GEMM epilogue (no per-edge dinv gather).

__global__ void hist(const int* __restrict__ dst, int* __restrict__ cnt, int E) {
    int i = blockIdx.x * blockDim.x + threadIdx.x;
    int e = i * 4;
    if (e + 4 <= E) {
        int4 d = ((const int4*)dst)[i];
        atomicAdd(&cnt[d.x], 1);
        atomicAdd(&cnt[d.y], 1);
        atomicAdd(&cnt[d.z], 1);
        atomicAdd(&cnt[d.w], 1);
    } else {
        for (; e < E; ++e) atomicAdd(&cnt[dst[e]], 1);
    }
}

// Per-block exclusive scan of cnt into rp; block totals into bsums; also dinv.
__global__ __launch_bounds__(1024) void scan1(const int* __restrict__ cnt, int* __restrict__ rp,
                                              int* __restrict__ bsums, float* __restrict__ dinv,
                                              int N) {
    __shared__ int s[1024];
    int tid = threadIdx.x;
    int gid = blockIdx.x * 1024 + tid;
    int v = (gid < N) ? cnt[gid] : 0;
    if (gid < N) dinv[gid] = rsqrtf((float)(v + 1));  // +1 self-loop; always > 0
    s[tid] = v;
    __syncthreads();
    for (int off = 1; off < 1024; off <<= 1) {
        int t = (tid >= off) ? s[tid - off] : 0;
        __syncthreads();
        s[tid] += t;
        __syncthreads();
    }
    if (gid < N) rp[gid] = s[tid] - v;  // exclusive
    if (tid == 1023) bsums[blockIdx.x] = s[1023];
}

// Exclusive scan of block sums (nb <= 256). Single block.
__global__ void scan2(int* __restrict__ bsums, int nb) {
    __shared__ int s[256];
    int tid = threadIdx.x;
    int v = (tid < nb) ? bsums[tid] : 0;
    s[tid] = v;
    __syncthreads();
    for (int off = 1; off < 256; off <<= 1) {
        int t = (tid >= off) ? s[tid - off] : 0;
        __syncthreads();
        s[tid] += t;
        __syncthreads();
    }
    if (tid < nb) bsums[tid] = s[tid] - v;
}

__global__ void scan3(int* __restrict__ rp, const int* __restrict__ bsums,
                      int* __restrict__ cursor, int N, int E) {
    int i = blockIdx.x * blockDim.x + threadIdx.x;
    if (i < N) {
        int r = rp[i] + bsums[i >> 10];
        rp[i] = r;
        cursor[i] = r;
    } else if (i == N) {
        rp[N] = E;
    }
}

__global__ void scatter(const int* __restrict__ src, const int* __restrict__ dst,
                        int* __restrict__ cursor, int* __restrict__ col, int E) {
    int i = blockIdx.x * blockDim.x + threadIdx.x;
    int e = i * 4;
    if (e + 4 <= E) {
        int4 s = ((const int4*)src)[i];
        int4 d = ((const int4*)dst)[i];
        col[atomicAdd(&cursor[d.x], 1)] = s.x;
        col[atomicAdd(&cursor[d.y], 1)] = s.y;
        col[atomicAdd(&cursor[d.z], 1)] = s.z;
        col[atomicAdd(&cursor[d.w], 1)] = s.w;
    } else {
        for (; e < E; ++e) {
            int pos = atomicAdd(&cursor[dst[e]], 1);
            col[pos] = src[e];
        }
    }
}

// H[row] = (X[row] @ W) * dinv[row]  — dinv scale folded into epilogue.
template <int CIN, int COUT>
__global__ void gemm_scaled(const float* __restrict__ X, const float* __restrict__ W,
                            const float* __restrict__ dinv, float* __restrict__ H, int N) {
    constexpr int R = 256 / COUT;
    __shared__ float Ws[CIN * COUT];
    __shared__ float Xs[R * CIN];
    int tid = threadIdx.x;
    for (int i = tid; i < CIN * COUT; i += 256) Ws[i] = W[i];
    int rowBase = blockIdx.x * R;
    for (int i = tid; i < R * CIN; i += 256) {
        int gr = rowBase + i / CIN;
        Xs[i] = (gr < N) ? X[(size_t)rowBase * CIN + i] : 0.f;
    }
    __syncthreads();
    int c = tid % COUT, r = tid / COUT;
    int row = rowBase + r;
    if (row >= N) return;
    float acc = 0.f;
#pragma unroll
    for (int k = 0; k < CIN; ++k) acc = fmaf(Xs[r * CIN + k], Ws[k * COUT + c], acc);
    H[(size_t)row * COUT + c] = acc * dinv[row];
}

// out[i] = dinv[i] * ( hs[i] + sum_{e: dst=i} hs[src_e] ) + bias,  hs = h*dinv row-scaled.
// lane = 4-channel quad -> 4 (C=64) / 8 (C=32) independent node-walks per wave;
// 4-way edge unroll -> up to 16 float4 gathers in flight per wave.
template <int C, bool RELU>
__global__ void aggregate4(const float* __restrict__ hsBase, const float* __restrict__ dinv,
                           const int* __restrict__ rp, const int* __restrict__ col,
                           const float* __restrict__ bias, float* __restrict__ outBase, int N) {
    constexpr int L = C / 4;  // float4 quads per row
    const float4* __restrict__ hs = (const float4*)hsBase;
    float4* __restrict__ out = (float4*)outBase;
    int t = blockIdx.x * blockDim.x + threadIdx.x;
    int node = t / L;
    int q = t % L;
    if (node >= N) return;
    float4 acc = hs[(size_t)node * L + q];  // self-loop term (pre-scaled)
    int e0 = rp[node], e1 = rp[node + 1];
    int e = e0;
    for (; e + 4 <= e1; e += 4) {
        int s0 = col[e + 0], s1 = col[e + 1], s2 = col[e + 2], s3 = col[e + 3];
        float4 v0 = hs[(size_t)s0 * L + q];
        float4 v1 = hs[(size_t)s1 * L + q];
        float4 v2 = hs[(size_t)s2 * L + q];
        float4 v3 = hs[(size_t)s3 * L + q];
        acc.x += (v0.x + v1.x) + (v2.x + v3.x);
        acc.y += (v0.y + v1.y) + (v2.y + v3.y);
        acc.z += (v0.z + v1.z) + (v2.z + v3.z);
        acc.w += (v0.w + v1.w) + (v2.w + v3.w);
    }
    for (; e < e1; ++e) {
        float4 v = hs[(size_t)col[e] * L + q];
        acc.x += v.x;
        acc.y += v.y;
        acc.z += v.z;
        acc.w += v.w;
    }
    float dn = dinv[node];
    float4 bb = ((const float4*)bias)[q];
    float4 r;
    r.x = fmaf(acc.x, dn, bb.x);
    r.y = fmaf(acc.y, dn, bb.y);
    r.z = fmaf(acc.z, dn, bb.z);
    r.w = fmaf(acc.w, dn, bb.w);
    if (RELU) {
        r.x = fmaxf(r.x, 0.f);
        r.y = fmaxf(r.y, 0.f);
        r.z = fmaxf(r.z, 0.f);
        r.w = fmaxf(r.w, 0.f);
    }
    out[(size_t)node * L + q] = r;
}

extern "C" void kernel_launch(void* const* d_in, const int* in_sizes, int n_in,
                              void* d_out, int out_size, void* d_ws, size_t ws_size,
                              hipStream_t stream) {
    const float* x = (const float*)d_in[0];
    const int* ei = (const int*)d_in[1];  // int64 in reference -> int32 from harness
    const float* W1 = (const float*)d_in[3];
    const float* b1 = (const float*)d_in[4];
    const float* W2 = (const float*)d_in[5];
    const float* b2 = (const float*)d_in[6];

    constexpr int CIN = 64, CHID = 64, COUT = 32;
    const int N = in_sizes[0] / CIN;
    const int E = in_sizes[1] / 2;
    const int* src = ei;
    const int* dst = ei + E;

    char* p = (char*)d_ws;
    auto carve = [&](size_t bytes) -> void* {
        void* q = (void*)p;
        p += (bytes + 255) & ~(size_t)255;
        return q;
    };
    int* cnt = (int*)carve((size_t)N * 4);       // indegree; reused as cursor
    int* rp = (int*)carve((size_t)(N + 1) * 4);  // CSR row pointers
    int* bsums = (int*)carve(256 * 4);
    int* col = (int*)carve((size_t)E * 4);  // CSR column (src) indices
    float* dinv = (float*)carve((size_t)N * 4);
    float* h1 = (float*)carve((size_t)N * CHID * 4);
    float* agg1 = (float*)carve((size_t)N * CHID * 4);
    int* cursor = cnt;  // cnt dead after scan1
    float* h2 = h1;     // h1 dead after aggregate1

    const int gE4 = ((E + 3) / 4 + 255) / 256;
    const int nb = (N + 1023) / 1024;  // 98 for N=100000 (must be <= 256)

    hipMemsetAsync(cnt, 0, (size_t)N * 4, stream);
    hist<<<gE4, 256, 0, stream>>>(dst, cnt, E);
    scan1<<<nb, 1024, 0, stream>>>(cnt, rp, bsums, dinv, N);
    scan2<<<1, 256, 0, stream>>>(bsums, nb);
    scan3<<<(N + 1 + 255) / 256, 256, 0, stream>>>(rp, bsums, cursor, N, E);
    scatter<<<gE4, 256, 0, stream>>>(src, dst, cursor, col, E);

    gemm_scaled<CIN, CHID><<<(N + 3) / 4, 256, 0, stream>>>(x, W1, dinv, h1, N);
    aggregate4<CHID, true>
        <<<((size_t)N * (CHID / 4) + 255) / 256, 256, 0, stream>>>(h1, dinv, rp, col, b1, agg1, N);
    gemm_scaled<CHID, COUT><<<(N + 7) / 8, 256, 0, stream>>>(agg1, W2, dinv, h2, N);
    aggregate4<COUT, false>
        <<<((size_t)N * (COUT / 4) + 255) / 256, 256, 0, stream>>>(h2, dinv, rp, col, b2,
                                                                   (float*)d_out, N);
}

// Round 4
// 292.612 us; speedup vs baseline: 2.0068x; 1.5262x over previous
//
#include <hip/hip_runtime.h>

// GCN 2-layer encoder on gfx950.
// R4: CSR build rewritten as bucket-binning (bucket = dst>>8, 256 nodes/bucket).
//   P1: LDS bucket hist -> 1 global atomic per (block,bucket) -> packed edge
//       (src<<8)|(dst&255) into per-bucket staging (contiguous runs).
//   scanB: exclusive scan of 391 bucket sizes (single block).
//   P2: one block per bucket; local deg/scan/cursor in LDS; writes rp, dinv,
//       col into a contiguous per-bucket region (no 64B write amplification).
// Replaces hist+scan1/2/3+scatter (3.2M device atomics, 108 MB col write-amp).
// Staging (12.8 MB) overlaps h1 (25.6 MB) — h1 written after P2 consumes it.

constexpr int CAP = 8192;    // per-bucket staging cap; E/NB ~ 4092, sigma ~ 64
constexpr int NBMAX = 512;   // NB = 391 for N = 100000

__global__ __launch_bounds__(256) void p1_bin(const int* __restrict__ src,
                                              const int* __restrict__ dst,
                                              int* __restrict__ bucketCursor,
                                              unsigned* __restrict__ staging, int E, int NB) {
    __shared__ int cnt[NBMAX];
    __shared__ int cur[NBMAX];
    int tid = threadIdx.x;
    for (int i = tid; i < NB; i += 256) cnt[i] = 0;
    __syncthreads();
    int e0 = blockIdx.x * 4096;
#pragma unroll
    for (int k = 0; k < 16; ++k) {
        int e = e0 + k * 256 + tid;
        if (e < E) atomicAdd(&cnt[dst[e] >> 8], 1);  // LDS atomic
    }
    __syncthreads();
    for (int i = tid; i < NB; i += 256) {
        int c = cnt[i];
        cur[i] = c ? atomicAdd(&bucketCursor[i], c) : 0;  // one global atomic per (block,bucket)
    }
    __syncthreads();
#pragma unroll
    for (int k = 0; k < 16; ++k) {
        int e = e0 + k * 256 + tid;
        if (e < E) {
            int d = dst[e];
            int b = d >> 8;
            int slot = atomicAdd(&cur[b], 1);  // LDS atomic; runs contiguous per bucket
            staging[(size_t)b * CAP + slot] = ((unsigned)src[e] << 8) | (unsigned)(d & 255);
        }
    }
}

// Exclusive scan of bucket sizes -> bucketBase[0..NB]; also rp[N]=E.
__global__ __launch_bounds__(512) void scan_buckets(const int* __restrict__ bucketCursor,
                                                    int* __restrict__ bucketBase,
                                                    int* __restrict__ rp, int NB, int N, int E) {
    __shared__ int s[NBMAX];
    int tid = threadIdx.x;
    int v = (tid < NB) ? bucketCursor[tid] : 0;
    s[tid] = v;
    __syncthreads();
    for (int off = 1; off < 512; off <<= 1) {
        int t = (tid >= off) ? s[tid - off] : 0;
        __syncthreads();
        s[tid] += t;
        __syncthreads();
    }
    if (tid < NB) bucketBase[tid] = s[tid] - v;
    if (tid == 0) {
        bucketBase[NB] = E;
        rp[N] = E;
    }
}

// One block per bucket: local hist/scan/cursor in LDS; emit rp, dinv, col.
__global__ __launch_bounds__(256) void p2_csr(const unsigned* __restrict__ staging,
                                              const int* __restrict__ bucketBase,
                                              int* __restrict__ rp, int* __restrict__ col,
                                              float* __restrict__ dinv, int N) {
    __shared__ int deg[256];
    __shared__ int scn[256];
    __shared__ int cur[256];
    int b = blockIdx.x;
    int tid = threadIdx.x;
    int base = bucketBase[b];
    int size = bucketBase[b + 1] - base;
    const unsigned* st = staging + (size_t)b * CAP;
    deg[tid] = 0;
    __syncthreads();
    for (int i = tid; i < size; i += 256) atomicAdd(&deg[st[i] & 255u], 1);
    __syncthreads();
    int g = b * 256 + tid;
    int d = deg[tid];
    if (g < N) dinv[g] = rsqrtf((float)(d + 1));  // +1 self-loop
    scn[tid] = d;
    __syncthreads();
    for (int off = 1; off < 256; off <<= 1) {
        int t = (tid >= off) ? scn[tid - off] : 0;
        __syncthreads();
        scn[tid] += t;
        __syncthreads();
    }
    int excl = scn[tid] - d;
    if (g < N) rp[g] = base + excl;
    cur[tid] = excl;
    __syncthreads();
    for (int i = tid; i < size; i += 256) {
        unsigned pk = st[i];
        int pos = atomicAdd(&cur[pk & 255u], 1);  // LDS atomic
        col[base + pos] = (int)(pk >> 8);         // within contiguous ~16KB region
    }
}

// H[row] = (X[row] @ W) * dinv[row]  — dinv scale folded into epilogue.
template <int CIN, int COUT>
__global__ void gemm_scaled(const float* __restrict__ X, const float* __restrict__ W,
                            const float* __restrict__ dinv, float* __restrict__ H, int N) {
    constexpr int R = 256 / COUT;
    __shared__ float Ws[CIN * COUT];
    __shared__ float Xs[R * CIN];
    int tid = threadIdx.x;
    for (int i = tid; i < CIN * COUT; i += 256) Ws[i] = W[i];
    int rowBase = blockIdx.x * R;
    for (int i = tid; i < R * CIN; i += 256) {
        int gr = rowBase + i / CIN;
        Xs[i] = (gr < N) ? X[(size_t)rowBase * CIN + i] : 0.f;
    }
    __syncthreads();
    int c = tid % COUT, r = tid / COUT;
    int row = rowBase + r;
    if (row >= N) return;
    float acc = 0.f;
#pragma unroll
    for (int k = 0; k < CIN; ++k) acc = fmaf(Xs[r * CIN + k], Ws[k * COUT + c], acc);
    H[(size_t)row * COUT + c] = acc * dinv[row];
}

// out[i] = dinv[i] * ( hs[i] + sum_{e: dst=i} hs[src_e] ) + bias,  hs pre-scaled.
template <int C, bool RELU>
__global__ void aggregate4(const float* __restrict__ hsBase, const float* __restrict__ dinv,
                           const int* __restrict__ rp, const int* __restrict__ col,
                           const float* __restrict__ bias, float* __restrict__ outBase, int N) {
    constexpr int L = C / 4;
    const float4* __restrict__ hs = (const float4*)hsBase;
    float4* __restrict__ out = (float4*)outBase;
    int t = blockIdx.x * blockDim.x + threadIdx.x;
    int node = t / L;
    int q = t % L;
    if (node >= N) return;
    float4 acc = hs[(size_t)node * L + q];  // self-loop term (pre-scaled)
    int e0 = rp[node], e1 = rp[node + 1];
    int e = e0;
    for (; e + 4 <= e1; e += 4) {
        int s0 = col[e + 0], s1 = col[e + 1], s2 = col[e + 2], s3 = col[e + 3];
        float4 v0 = hs[(size_t)s0 * L + q];
        float4 v1 = hs[(size_t)s1 * L + q];
        float4 v2 = hs[(size_t)s2 * L + q];
        float4 v3 = hs[(size_t)s3 * L + q];
        acc.x += (v0.x + v1.x) + (v2.x + v3.x);
        acc.y += (v0.y + v1.y) + (v2.y + v3.y);
        acc.z += (v0.z + v1.z) + (v2.z + v3.z);
        acc.w += (v0.w + v1.w) + (v2.w + v3.w);
    }
    for (; e < e1; ++e) {
        float4 v = hs[(size_t)col[e] * L + q];
        acc.x += v.x;
        acc.y += v.y;
        acc.z += v.z;
        acc.w += v.w;
    }
    float dn = dinv[node];
    float4 bb = ((const float4*)bias)[q];
    float4 r;
    r.x = fmaf(acc.x, dn, bb.x);
    r.y = fmaf(acc.y, dn, bb.y);
    r.z = fmaf(acc.z, dn, bb.z);
    r.w = fmaf(acc.w, dn, bb.w);
    if (RELU) {
        r.x = fmaxf(r.x, 0.f);
        r.y = fmaxf(r.y, 0.f);
        r.z = fmaxf(r.z, 0.f);
        r.w = fmaxf(r.w, 0.f);
    }
    out[(size_t)node * L + q] = r;
}

extern "C" void kernel_launch(void* const* d_in, const int* in_sizes, int n_in,
                              void* d_out, int out_size, void* d_ws, size_t ws_size,
                              hipStream_t stream) {
    const float* x = (const float*)d_in[0];
    const int* ei = (const int*)d_in[1];  // int64 in reference -> int32 from harness
    const float* W1 = (const float*)d_in[3];
    const float* b1 = (const float*)d_in[4];
    const float* W2 = (const float*)d_in[5];
    const float* b2 = (const float*)d_in[6];

    constexpr int CIN = 64, CHID = 64, COUT = 32;
    const int N = in_sizes[0] / CIN;
    const int E = in_sizes[1] / 2;
    const int* src = ei;
    const int* dst = ei + E;
    const int NB = (N + 255) >> 8;  // 391 buckets of 256 nodes

    char* p = (char*)d_ws;
    auto carve = [&](size_t bytes) -> void* {
        void* q = (void*)p;
        p += (bytes + 255) & ~(size_t)255;
        return q;
    };
    int* bucketCursor = (int*)carve((size_t)NB * 4);
    int* bucketBase = (int*)carve((size_t)(NB + 1) * 4);
    int* rp = (int*)carve((size_t)(N + 1) * 4);
    int* col = (int*)carve((size_t)E * 4);
    float* dinv = (float*)carve((size_t)N * 4);
    float* h1 = (float*)carve((size_t)N * CHID * 4);
    float* agg1 = (float*)carve((size_t)N * CHID * 4);
    unsigned* staging = (unsigned*)h1;  // 12.8 MB staging overlaps h1 (dead before gemm1)
    float* h2 = h1;                     // h1 dead after aggregate1

    hipMemsetAsync(bucketCursor, 0, (size_t)NB * 4, stream);
    p1_bin<<<(E + 4095) / 4096, 256, 0, stream>>>(src, dst, bucketCursor, staging, E, NB);
    scan_buckets<<<1, 512, 0, stream>>>(bucketCursor, bucketBase, rp, NB, N, E);
    p2_csr<<<NB, 256, 0, stream>>>(staging, bucketBase, rp, col, dinv, N);

    gemm_scaled<CIN, CHID><<<(N + 3) / 4, 256, 0, stream>>>(x, W1, dinv, h1, N);
    aggregate4<CHID, true>
        <<<((size_t)N * (CHID / 4) + 255) / 256, 256, 0, stream>>>(h1, dinv, rp, col, b1, agg1, N);
    gemm_scaled<CHID, COUT><<<(N + 7) / 8, 256, 0, stream>>>(agg1, W2, dinv, h2, N);
    aggregate4<COUT, false>
        <<<((size_t)N * (COUT / 4) + 255) / 256, 256, 0, stream>>>(h2, dinv, rp, col, b2,
                                                                   (float*)d_out, N);
}

// Round 5
// 229.771 us; speedup vs baseline: 2.5556x; 1.2735x over previous
//
#include <hip/hip_runtime.h>

// GCN 2-layer encoder on gfx950.
// R5: (a) register-tiled GEMM (4xTC per thread, b128 W reads + broadcast
//     stride-65 X reads) replacing the LDS-bound 1-output/thread gemm;
//     (b) h1 stored bf16 (halves layer-1 gather traffic; fp32 accumulate).
// CSR build (bucket-binning) unchanged from R4.

constexpr int CAP = 8192;   // per-bucket staging cap; E/NB ~ 4092
constexpr int NBMAX = 512;  // NB = 391 for N = 100000

__device__ inline unsigned short f2bf(float f) {  // RNE f32->bf16 (finite inputs)
    unsigned u = __float_as_uint(f);
    u += 0x7fff + ((u >> 16) & 1);
    return (unsigned short)(u >> 16);
}
__device__ inline float bflo(unsigned u) { return __uint_as_float(u << 16); }
__device__ inline float bfhi(unsigned u) { return __uint_as_float(u & 0xffff0000u); }

__global__ __launch_bounds__(256) void p1_bin(const int* __restrict__ src,
                                              const int* __restrict__ dst,
                                              int* __restrict__ bucketCursor,
                                              unsigned* __restrict__ staging, int E, int NB) {
    __shared__ int cnt[NBMAX];
    __shared__ int cur[NBMAX];
    int tid = threadIdx.x;
    for (int i = tid; i < NB; i += 256) cnt[i] = 0;
    __syncthreads();
    int e0 = blockIdx.x * 4096;
#pragma unroll
    for (int k = 0; k < 16; ++k) {
        int e = e0 + k * 256 + tid;
        if (e < E) atomicAdd(&cnt[dst[e] >> 8], 1);  // LDS atomic
    }
    __syncthreads();
    for (int i = tid; i < NB; i += 256) {
        int c = cnt[i];
        cur[i] = c ? atomicAdd(&bucketCursor[i], c) : 0;  // 1 global atomic/(block,bucket)
    }
    __syncthreads();
#pragma unroll
    for (int k = 0; k < 16; ++k) {
        int e = e0 + k * 256 + tid;
        if (e < E) {
            int d = dst[e];
            int b = d >> 8;
            int slot = atomicAdd(&cur[b], 1);  // LDS atomic; runs contiguous per bucket
            staging[(size_t)b * CAP + slot] = ((unsigned)src[e] << 8) | (unsigned)(d & 255);
        }
    }
}

__global__ __launch_bounds__(512) void scan_buckets(const int* __restrict__ bucketCursor,
                                                    int* __restrict__ bucketBase,
                                                    int* __restrict__ rp, int NB, int N, int E) {
    __shared__ int s[NBMAX];
    int tid = threadIdx.x;
    int v = (tid < NB) ? bucketCursor[tid] : 0;
    s[tid] = v;
    __syncthreads();
    for (int off = 1; off < 512; off <<= 1) {
        int t = (tid >= off) ? s[tid - off] : 0;
        __syncthreads();
        s[tid] += t;
        __syncthreads();
    }
    if (tid < NB) bucketBase[tid] = s[tid] - v;
    if (tid == 0) {
        bucketBase[NB] = E;
        rp[N] = E;
    }
}

__global__ __launch_bounds__(256) void p2_csr(const unsigned* __restrict__ staging,
                                              const int* __restrict__ bucketBase,
                                              int* __restrict__ rp, int* __restrict__ col,
                                              float* __restrict__ dinv, int N) {
    __shared__ int deg[256];
    __shared__ int scn[256];
    __shared__ int cur[256];
    int b = blockIdx.x;
    int tid = threadIdx.x;
    int base = bucketBase[b];
    int size = bucketBase[b + 1] - base;
    const unsigned* st = staging + (size_t)b * CAP;
    deg[tid] = 0;
    __syncthreads();
    for (int i = tid; i < size; i += 256) atomicAdd(&deg[st[i] & 255u], 1);
    __syncthreads();
    int g = b * 256 + tid;
    int d = deg[tid];
    if (g < N) dinv[g] = rsqrtf((float)(d + 1));  // +1 self-loop
    scn[tid] = d;
    __syncthreads();
    for (int off = 1; off < 256; off <<= 1) {
        int t = (tid >= off) ? scn[tid - off] : 0;
        __syncthreads();
        scn[tid] += t;
        __syncthreads();
    }
    int excl = scn[tid] - d;
    if (g < N) rp[g] = base + excl;
    cur[tid] = excl;
    __syncthreads();
    for (int i = tid; i < size; i += 256) {
        unsigned pk = st[i];
        int pos = atomicAdd(&cur[pk & 255u], 1);
        col[base + pos] = (int)(pk >> 8);
    }
}

// H[row] = (X[row] @ W) * dinv[row]; 128-row tile, thread = 4 rows x TC cols.
// Xs stride-65 pad: per-wave b32 reads hit 8 distinct banks (conflict-free,
// broadcast across col-groups). W reads are b128, 2-way worst (free).
template <int COUT, int TC, bool BF16OUT>
__global__ __launch_bounds__(256) void gemm_tile(const float* __restrict__ X,
                                                 const float* __restrict__ W,
                                                 const float* __restrict__ dinv,
                                                 void* __restrict__ Hout, int N) {
    constexpr int RPB = 128;
    constexpr int CG = COUT / TC;  // = 8 for both instantiations
    constexpr int XS = 65;
    __shared__ float Xs[RPB * XS];
    __shared__ float Ws[64 * COUT];
    int tid = threadIdx.x;
    int rowBase = blockIdx.x * RPB;
    const float4* Wv = (const float4*)W;
    float4* Wsv = (float4*)Ws;
    for (int i = tid; i < 64 * COUT / 4; i += 256) Wsv[i] = Wv[i];
    const float4* Xv = (const float4*)X;
    for (int v = tid; v < RPB * 16; v += 256) {
        int r = v >> 4, j = v & 15;
        int gr = rowBase + r;
        float4 t = make_float4(0.f, 0.f, 0.f, 0.f);
        if (gr < N) t = Xv[(size_t)gr * 16 + j];
        int b = r * XS + j * 4;
        Xs[b] = t.x;
        Xs[b + 1] = t.y;
        Xs[b + 2] = t.z;
        Xs[b + 3] = t.w;
    }
    __syncthreads();
    int cg = tid % CG, rg = tid / CG;
    int c0 = cg * TC, r0 = rg * 4;
    float acc[4][TC];
#pragma unroll
    for (int i = 0; i < 4; ++i)
#pragma unroll
        for (int j = 0; j < TC; ++j) acc[i][j] = 0.f;
#pragma unroll 8
    for (int k = 0; k < 64; ++k) {
        float4 w0 = *(const float4*)&Ws[k * COUT + c0];
        float4 w1;
        if (TC == 8) w1 = *(const float4*)&Ws[k * COUT + c0 + 4];
        float xr[4];
#pragma unroll
        for (int i = 0; i < 4; ++i) xr[i] = Xs[(r0 + i) * XS + k];
#pragma unroll
        for (int i = 0; i < 4; ++i) {
            acc[i][0] = fmaf(xr[i], w0.x, acc[i][0]);
            acc[i][1] = fmaf(xr[i], w0.y, acc[i][1]);
            acc[i][2] = fmaf(xr[i], w0.z, acc[i][2]);
            acc[i][3] = fmaf(xr[i], w0.w, acc[i][3]);
            if (TC == 8) {
                acc[i][4] = fmaf(xr[i], w1.x, acc[i][4]);
                acc[i][5] = fmaf(xr[i], w1.y, acc[i][5]);
                acc[i][6] = fmaf(xr[i], w1.z, acc[i][6]);
                acc[i][7] = fmaf(xr[i], w1.w, acc[i][7]);
            }
        }
    }
#pragma unroll
    for (int i = 0; i < 4; ++i) {
        int row = rowBase + r0 + i;
        if (row >= N) continue;
        float dn = dinv[row];
        if (BF16OUT) {
            unsigned pk[TC / 2];
#pragma unroll
            for (int j = 0; j < TC / 2; ++j) {
                unsigned lo = f2bf(acc[i][2 * j] * dn);
                unsigned hi = f2bf(acc[i][2 * j + 1] * dn);
                pk[j] = lo | (hi << 16);
            }
            if (TC == 8) {
                uint4 v = make_uint4(pk[0], pk[1], pk[2], pk[3]);
                *(uint4*)((unsigned short*)Hout + (size_t)row * COUT + c0) = v;
            } else {
                uint2 v = make_uint2(pk[0], pk[1]);
                *(uint2*)((unsigned short*)Hout + (size_t)row * COUT + c0) = v;
            }
        } else {
#pragma unroll
            for (int j4 = 0; j4 < TC / 4; ++j4) {
                float4 v = make_float4(acc[i][4 * j4] * dn, acc[i][4 * j4 + 1] * dn,
                                       acc[i][4 * j4 + 2] * dn, acc[i][4 * j4 + 3] * dn);
                *(float4*)((float*)Hout + (size_t)row * COUT + c0 + 4 * j4) = v;
            }
        }
    }
}

// Layer-1 aggregate: bf16 rows (64 ch), 8 ch/thread via uint4 gathers -> 8
// independent node-walks per wave; fp32 accumulate; out fp32 (+bias, relu).
__global__ __launch_bounds__(256) void aggregate_bf16(
    const uint4* __restrict__ hs, const float* __restrict__ dinv, const int* __restrict__ rp,
    const int* __restrict__ col, const float* __restrict__ bias, float* __restrict__ out, int N) {
    int t = blockIdx.x * blockDim.x + threadIdx.x;
    int node = t >> 3, q = t & 7;
    if (node >= N) return;
    float acc[8];
    uint4 u = hs[(size_t)node * 8 + q];  // self-loop term (pre-scaled)
    acc[0] = bflo(u.x); acc[1] = bfhi(u.x);
    acc[2] = bflo(u.y); acc[3] = bfhi(u.y);
    acc[4] = bflo(u.z); acc[5] = bfhi(u.z);
    acc[6] = bflo(u.w); acc[7] = bfhi(u.w);
    int e0 = rp[node], e1 = rp[node + 1];
    int e = e0;
#define ACC8(U)                                     \
    acc[0] += bflo(U.x); acc[1] += bfhi(U.x);       \
    acc[2] += bflo(U.y); acc[3] += bfhi(U.y);       \
    acc[4] += bflo(U.z); acc[5] += bfhi(U.z);       \
    acc[6] += bflo(U.w); acc[7] += bfhi(U.w);
    for (; e + 4 <= e1; e += 4) {
        int s0 = col[e], s1 = col[e + 1], s2 = col[e + 2], s3 = col[e + 3];
        uint4 u0 = hs[(size_t)s0 * 8 + q];
        uint4 u1 = hs[(size_t)s1 * 8 + q];
        uint4 u2 = hs[(size_t)s2 * 8 + q];
        uint4 u3 = hs[(size_t)s3 * 8 + q];
        ACC8(u0) ACC8(u1) ACC8(u2) ACC8(u3)
    }
    for (; e < e1; ++e) {
        uint4 uu = hs[(size_t)col[e] * 8 + q];
        ACC8(uu)
    }
#undef ACC8
    float dn = dinv[node];
    const float4* bv = (const float4*)bias;
    float4 b0 = bv[q * 2], b1 = bv[q * 2 + 1];
    float4 r0, r1;
    r0.x = fmaxf(fmaf(acc[0], dn, b0.x), 0.f);
    r0.y = fmaxf(fmaf(acc[1], dn, b0.y), 0.f);
    r0.z = fmaxf(fmaf(acc[2], dn, b0.z), 0.f);
    r0.w = fmaxf(fmaf(acc[3], dn, b0.w), 0.f);
    r1.x = fmaxf(fmaf(acc[4], dn, b1.x), 0.f);
    r1.y = fmaxf(fmaf(acc[5], dn, b1.y), 0.f);
    r1.z = fmaxf(fmaf(acc[6], dn, b1.z), 0.f);
    r1.w = fmaxf(fmaf(acc[7], dn, b1.w), 0.f);
    float4* ov = (float4*)(out + (size_t)node * 64 + q * 8);
    ov[0] = r0;
    ov[1] = r1;
}

// Layer-2 aggregate: fp32 rows (32 ch), float4 gathers, 8 node-walks/wave.
template <int C, bool RELU>
__global__ void aggregate4(const float* __restrict__ hsBase, const float* __restrict__ dinv,
                           const int* __restrict__ rp, const int* __restrict__ col,
                           const float* __restrict__ bias, float* __restrict__ outBase, int N) {
    constexpr int L = C / 4;
    const float4* __restrict__ hs = (const float4*)hsBase;
    float4* __restrict__ out = (float4*)outBase;
    int t = blockIdx.x * blockDim.x + threadIdx.x;
    int node = t / L;
    int q = t % L;
    if (node >= N) return;
    float4 acc = hs[(size_t)node * L + q];
    int e0 = rp[node], e1 = rp[node + 1];
    int e = e0;
    for (; e + 4 <= e1; e += 4) {
        int s0 = col[e + 0], s1 = col[e + 1], s2 = col[e + 2], s3 = col[e + 3];
        float4 v0 = hs[(size_t)s0 * L + q];
        float4 v1 = hs[(size_t)s1 * L + q];
        float4 v2 = hs[(size_t)s2 * L + q];
        float4 v3 = hs[(size_t)s3 * L + q];
        acc.x += (v0.x + v1.x) + (v2.x + v3.x);
        acc.y += (v0.y + v1.y) + (v2.y + v3.y);
        acc.z += (v0.z + v1.z) + (v2.z + v3.z);
        acc.w += (v0.w + v1.w) + (v2.w + v3.w);
    }
    for (; e < e1; ++e) {
        float4 v = hs[(size_t)col[e] * L + q];
        acc.x += v.x;
        acc.y += v.y;
        acc.z += v.z;
        acc.w += v.w;
    }
    float dn = dinv[node];
    float4 bb = ((const float4*)bias)[q];
    float4 r;
    r.x = fmaf(acc.x, dn, bb.x);
    r.y = fmaf(acc.y, dn, bb.y);
    r.z = fmaf(acc.z, dn, bb.z);
    r.w = fmaf(acc.w, dn, bb.w);
    if (RELU) {
        r.x = fmaxf(r.x, 0.f);
        r.y = fmaxf(r.y, 0.f);
        r.z = fmaxf(r.z, 0.f);
        r.w = fmaxf(r.w, 0.f);
    }
    out[(size_t)node * L + q] = r;
}

extern "C" void kernel_launch(void* const* d_in, const int* in_sizes, int n_in,
                              void* d_out, int out_size, void* d_ws, size_t ws_size,
                              hipStream_t stream) {
    const float* x = (const float*)d_in[0];
    const int* ei = (const int*)d_in[1];  // int64 in reference -> int32 from harness
    const float* W1 = (const float*)d_in[3];
    const float* b1 = (const float*)d_in[4];
    const float* W2 = (const float*)d_in[5];
    const float* b2 = (const float*)d_in[6];

    constexpr int CIN = 64, CHID = 64, COUT = 32;
    const int N = in_sizes[0] / CIN;
    const int E = in_sizes[1] / 2;
    const int* src = ei;
    const int* dst = ei + E;
    const int NB = (N + 255) >> 8;

    char* p = (char*)d_ws;
    auto carve = [&](size_t bytes) -> void* {
        void* q = (void*)p;
        p += (bytes + 255) & ~(size_t)255;
        return q;
    };
    int* bucketCursor = (int*)carve((size_t)NB * 4);
    int* bucketBase = (int*)carve((size_t)(NB + 1) * 4);
    int* rp = (int*)carve((size_t)(N + 1) * 4);
    int* col = (int*)carve((size_t)E * 4);
    float* dinv = (float*)carve((size_t)N * 4);
    unsigned* staging = (unsigned*)carve((size_t)NB * CAP * 4);  // 12.8 MB
    unsigned short* h1 = (unsigned short*)carve((size_t)N * CHID * 2);  // bf16
    float* agg1 = (float*)carve((size_t)N * CHID * 4);
    float* h2 = (float*)staging;  // staging dead after p2_csr; 12.8 MB each

    hipMemsetAsync(bucketCursor, 0, (size_t)NB * 4, stream);
    p1_bin<<<(E + 4095) / 4096, 256, 0, stream>>>(src, dst, bucketCursor, staging, E, NB);
    scan_buckets<<<1, 512, 0, stream>>>(bucketCursor, bucketBase, rp, NB, N, E);
    p2_csr<<<NB, 256, 0, stream>>>(staging, bucketBase, rp, col, dinv, N);

    gemm_tile<CHID, 8, true><<<(N + 127) / 128, 256, 0, stream>>>(x, W1, dinv, (void*)h1, N);
    aggregate_bf16<<<((size_t)N * 8 + 255) / 256, 256, 0, stream>>>((const uint4*)h1, dinv, rp,
                                                                    col, b1, agg1, N);
    gemm_tile<COUT, 4, false><<<(N + 127) / 128, 256, 0, stream>>>(agg1, W2, dinv, (void*)h2, N);
    aggregate4<COUT, false>
        <<<((size_t)N * (COUT / 4) + 255) / 256, 256, 0, stream>>>(h2, dinv, rp, col, b2,
                                                                   (float*)d_out, N);
}

// Round 6
// 207.595 us; speedup vs baseline: 2.8286x; 1.1068x over previous
//
#include <hip/hip_runtime.h>

// GCN 2-layer encoder on gfx950.
// R6: fuse aggregate1+gemm2 (kills the 51 MB agg1 round-trip); h2 stored bf16
//     (halves agg2 gather bytes; 16 node-walks/wave in agg2).
// Pipeline: memset -> p1_bin -> scan_buckets -> p2_csr -> gemm1(bf16 h1)
//           -> agg1_gemm2(bf16 h2) -> agg2 -> d_out (fp32).

constexpr int CAP = 8192;   // per-bucket staging cap; E/NB ~ 4092
constexpr int NBMAX = 512;  // NB = 391 for N = 100000

__device__ inline unsigned short f2bf(float f) {  // RNE f32->bf16 (finite inputs)
    unsigned u = __float_as_uint(f);
    u += 0x7fff + ((u >> 16) & 1);
    return (unsigned short)(u >> 16);
}
__device__ inline float bflo(unsigned u) { return __uint_as_float(u << 16); }
__device__ inline float bfhi(unsigned u) { return __uint_as_float(u & 0xffff0000u); }

__global__ __launch_bounds__(256) void p1_bin(const int* __restrict__ src,
                                              const int* __restrict__ dst,
                                              int* __restrict__ bucketCursor,
                                              unsigned* __restrict__ staging, int E, int NB) {
    __shared__ int cnt[NBMAX];
    __shared__ int cur[NBMAX];
    int tid = threadIdx.x;
    for (int i = tid; i < NB; i += 256) cnt[i] = 0;
    __syncthreads();
    int e0 = blockIdx.x * 4096;
#pragma unroll
    for (int k = 0; k < 16; ++k) {
        int e = e0 + k * 256 + tid;
        if (e < E) atomicAdd(&cnt[dst[e] >> 8], 1);  // LDS atomic
    }
    __syncthreads();
    for (int i = tid; i < NB; i += 256) {
        int c = cnt[i];
        cur[i] = c ? atomicAdd(&bucketCursor[i], c) : 0;  // 1 global atomic/(block,bucket)
    }
    __syncthreads();
#pragma unroll
    for (int k = 0; k < 16; ++k) {
        int e = e0 + k * 256 + tid;
        if (e < E) {
            int d = dst[e];
            int b = d >> 8;
            int slot = atomicAdd(&cur[b], 1);  // LDS atomic; runs contiguous per bucket
            staging[(size_t)b * CAP + slot] = ((unsigned)src[e] << 8) | (unsigned)(d & 255);
        }
    }
}

__global__ __launch_bounds__(512) void scan_buckets(const int* __restrict__ bucketCursor,
                                                    int* __restrict__ bucketBase,
                                                    int* __restrict__ rp, int NB, int N, int E) {
    __shared__ int s[NBMAX];
    int tid = threadIdx.x;
    int v = (tid < NB) ? bucketCursor[tid] : 0;
    s[tid] = v;
    __syncthreads();
    for (int off = 1; off < 512; off <<= 1) {
        int t = (tid >= off) ? s[tid - off] : 0;
        __syncthreads();
        s[tid] += t;
        __syncthreads();
    }
    if (tid < NB) bucketBase[tid] = s[tid] - v;
    if (tid == 0) {
        bucketBase[NB] = E;
        rp[N] = E;
    }
}

__global__ __launch_bounds__(256) void p2_csr(const unsigned* __restrict__ staging,
                                              const int* __restrict__ bucketBase,
                                              int* __restrict__ rp, int* __restrict__ col,
                                              float* __restrict__ dinv, int N) {
    __shared__ int deg[256];
    __shared__ int scn[256];
    __shared__ int cur[256];
    int b = blockIdx.x;
    int tid = threadIdx.x;
    int base = bucketBase[b];
    int size = bucketBase[b + 1] - base;
    const unsigned* st = staging + (size_t)b * CAP;
    deg[tid] = 0;
    __syncthreads();
    for (int i = tid; i < size; i += 256) atomicAdd(&deg[st[i] & 255u], 1);
    __syncthreads();
    int g = b * 256 + tid;
    int d = deg[tid];
    if (g < N) dinv[g] = rsqrtf((float)(d + 1));  // +1 self-loop
    scn[tid] = d;
    __syncthreads();
    for (int off = 1; off < 256; off <<= 1) {
        int t = (tid >= off) ? scn[tid - off] : 0;
        __syncthreads();
        scn[tid] += t;
        __syncthreads();
    }
    int excl = scn[tid] - d;
    if (g < N) rp[g] = base + excl;
    cur[tid] = excl;
    __syncthreads();
    for (int i = tid; i < size; i += 256) {
        unsigned pk = st[i];
        int pos = atomicAdd(&cur[pk & 255u], 1);
        col[base + pos] = (int)(pk >> 8);
    }
}

// h1[row] = bf16( (X[row] @ W1) * dinv[row] ); 128-row tile, thread = 4 rows x 8 cols.
__global__ __launch_bounds__(256) void gemm1(const float* __restrict__ X,
                                             const float* __restrict__ W,
                                             const float* __restrict__ dinv,
                                             unsigned short* __restrict__ Hout, int N) {
    constexpr int XS = 65;
    __shared__ float Xs[128 * XS];
    __shared__ float Ws[64 * 64];
    int tid = threadIdx.x;
    int rowBase = blockIdx.x * 128;
    const float4* Wv = (const float4*)W;
    float4* Wsv = (float4*)Ws;
    for (int i = tid; i < 64 * 64 / 4; i += 256) Wsv[i] = Wv[i];
    const float4* Xv = (const float4*)X;
    for (int v = tid; v < 128 * 16; v += 256) {
        int r = v >> 4, j = v & 15;
        int gr = rowBase + r;
        float4 t = make_float4(0.f, 0.f, 0.f, 0.f);
        if (gr < N) t = Xv[(size_t)gr * 16 + j];
        int b = r * XS + j * 4;
        Xs[b] = t.x;
        Xs[b + 1] = t.y;
        Xs[b + 2] = t.z;
        Xs[b + 3] = t.w;
    }
    __syncthreads();
    int cg = tid % 8, rg = tid / 8;
    int c0 = cg * 8, r0 = rg * 4;
    float acc[4][8];
#pragma unroll
    for (int i = 0; i < 4; ++i)
#pragma unroll
        for (int j = 0; j < 8; ++j) acc[i][j] = 0.f;
#pragma unroll 8
    for (int k = 0; k < 64; ++k) {
        float4 w0 = *(const float4*)&Ws[k * 64 + c0];
        float4 w1 = *(const float4*)&Ws[k * 64 + c0 + 4];
        float xr[4];
#pragma unroll
        for (int i = 0; i < 4; ++i) xr[i] = Xs[(r0 + i) * XS + k];
#pragma unroll
        for (int i = 0; i < 4; ++i) {
            acc[i][0] = fmaf(xr[i], w0.x, acc[i][0]);
            acc[i][1] = fmaf(xr[i], w0.y, acc[i][1]);
            acc[i][2] = fmaf(xr[i], w0.z, acc[i][2]);
            acc[i][3] = fmaf(xr[i], w0.w, acc[i][3]);
            acc[i][4] = fmaf(xr[i], w1.x, acc[i][4]);
            acc[i][5] = fmaf(xr[i], w1.y, acc[i][5]);
            acc[i][6] = fmaf(xr[i], w1.z, acc[i][6]);
            acc[i][7] = fmaf(xr[i], w1.w, acc[i][7]);
        }
    }
#pragma unroll
    for (int i = 0; i < 4; ++i) {
        int row = rowBase + r0 + i;
        if (row >= N) continue;
        float dn = dinv[row];
        unsigned pk[4];
#pragma unroll
        for (int j = 0; j < 4; ++j) {
            unsigned lo = f2bf(acc[i][2 * j] * dn);
            unsigned hi = f2bf(acc[i][2 * j + 1] * dn);
            pk[j] = lo | (hi << 16);
        }
        *(uint4*)(Hout + (size_t)row * 64 + c0) = make_uint4(pk[0], pk[1], pk[2], pk[3]);
    }
}

// Fused layer-1 aggregate + layer-2 linear:
//   a1 = relu(dinv_i*(hs1[i] + sum hs1[col]) + b1)   (8 bf16 ch/thread, fp32 acc)
//   h2s[i] = bf16( (a1 @ W2) * dinv_i )              (LDS exchange, 4 out-ch/thread)
// 32 nodes/block, 8 threads/node. Row stride 68 floats: b128 row reads land on
// banks 4r..4r+3 across the 8 node-groups -> all 32 banks 2-way (free).
__global__ __launch_bounds__(256) void agg1_gemm2(
    const uint4* __restrict__ hs1, const float* __restrict__ dinv, const int* __restrict__ rp,
    const int* __restrict__ col, const float* __restrict__ b1, const float* __restrict__ W2,
    unsigned short* __restrict__ h2, int N) {
    constexpr int RS = 68;
    __shared__ float rows[32 * RS];
    __shared__ float Ws2[64 * 32];
    int tid = threadIdx.x;
    const float4* W2v = (const float4*)W2;
    float4* Ws2v = (float4*)Ws2;
    for (int i = tid; i < 64 * 32 / 4; i += 256) Ws2v[i] = W2v[i];

    int r = tid >> 3, q = tid & 7;
    int node = blockIdx.x * 32 + r;
    float acc[8];
#pragma unroll
    for (int j = 0; j < 8; ++j) acc[j] = 0.f;
    float dn = 0.f;
    if (node < N) {
        dn = dinv[node];
        uint4 u = hs1[(size_t)node * 8 + q];  // self-loop (pre-scaled)
        acc[0] = bflo(u.x); acc[1] = bfhi(u.x);
        acc[2] = bflo(u.y); acc[3] = bfhi(u.y);
        acc[4] = bflo(u.z); acc[5] = bfhi(u.z);
        acc[6] = bflo(u.w); acc[7] = bfhi(u.w);
        int e0 = rp[node], e1 = rp[node + 1];
        int e = e0;
#define ACC8(U)                               \
    acc[0] += bflo(U.x); acc[1] += bfhi(U.x); \
    acc[2] += bflo(U.y); acc[3] += bfhi(U.y); \
    acc[4] += bflo(U.z); acc[5] += bfhi(U.z); \
    acc[6] += bflo(U.w); acc[7] += bfhi(U.w);
        for (; e + 4 <= e1; e += 4) {
            int s0 = col[e], s1 = col[e + 1], s2 = col[e + 2], s3 = col[e + 3];
            uint4 u0 = hs1[(size_t)s0 * 8 + q];
            uint4 u1 = hs1[(size_t)s1 * 8 + q];
            uint4 u2 = hs1[(size_t)s2 * 8 + q];
            uint4 u3 = hs1[(size_t)s3 * 8 + q];
            ACC8(u0) ACC8(u1) ACC8(u2) ACC8(u3)
        }
        for (; e < e1; ++e) {
            uint4 uu = hs1[(size_t)col[e] * 8 + q];
            ACC8(uu)
        }
#undef ACC8
        const float4* bv = (const float4*)b1;
        float4 bb0 = bv[q * 2], bb1 = bv[q * 2 + 1];
        acc[0] = fmaxf(fmaf(acc[0], dn, bb0.x), 0.f);
        acc[1] = fmaxf(fmaf(acc[1], dn, bb0.y), 0.f);
        acc[2] = fmaxf(fmaf(acc[2], dn, bb0.z), 0.f);
        acc[3] = fmaxf(fmaf(acc[3], dn, bb0.w), 0.f);
        acc[4] = fmaxf(fmaf(acc[4], dn, bb1.x), 0.f);
        acc[5] = fmaxf(fmaf(acc[5], dn, bb1.y), 0.f);
        acc[6] = fmaxf(fmaf(acc[6], dn, bb1.z), 0.f);
        acc[7] = fmaxf(fmaf(acc[7], dn, bb1.w), 0.f);
    }
    float* myrow = &rows[r * RS + q * 8];
    *(float4*)myrow = make_float4(acc[0], acc[1], acc[2], acc[3]);
    *(float4*)(myrow + 4) = make_float4(acc[4], acc[5], acc[6], acc[7]);
    __syncthreads();

    if (node >= N) return;
    int c0 = q * 4;
    float acc2[4] = {0.f, 0.f, 0.f, 0.f};
    const float* row = &rows[r * RS];
#pragma unroll
    for (int k4 = 0; k4 < 16; ++k4) {
        float4 xq = *(const float4*)&row[k4 * 4];
        float4 wa = *(const float4*)&Ws2[(k4 * 4 + 0) * 32 + c0];
        float4 wb = *(const float4*)&Ws2[(k4 * 4 + 1) * 32 + c0];
        float4 wc = *(const float4*)&Ws2[(k4 * 4 + 2) * 32 + c0];
        float4 wd = *(const float4*)&Ws2[(k4 * 4 + 3) * 32 + c0];
        acc2[0] = fmaf(xq.x, wa.x, acc2[0]);
        acc2[1] = fmaf(xq.x, wa.y, acc2[1]);
        acc2[2] = fmaf(xq.x, wa.z, acc2[2]);
        acc2[3] = fmaf(xq.x, wa.w, acc2[3]);
        acc2[0] = fmaf(xq.y, wb.x, acc2[0]);
        acc2[1] = fmaf(xq.y, wb.y, acc2[1]);
        acc2[2] = fmaf(xq.y, wb.z, acc2[2]);
        acc2[3] = fmaf(xq.y, wb.w, acc2[3]);
        acc2[0] = fmaf(xq.z, wc.x, acc2[0]);
        acc2[1] = fmaf(xq.z, wc.y, acc2[1]);
        acc2[2] = fmaf(xq.z, wc.z, acc2[2]);
        acc2[3] = fmaf(xq.z, wc.w, acc2[3]);
        acc2[0] = fmaf(xq.w, wd.x, acc2[0]);
        acc2[1] = fmaf(xq.w, wd.y, acc2[1]);
        acc2[2] = fmaf(xq.w, wd.z, acc2[2]);
        acc2[3] = fmaf(xq.w, wd.w, acc2[3]);
    }
    unsigned p0 = f2bf(acc2[0] * dn) | ((unsigned)f2bf(acc2[1] * dn) << 16);
    unsigned p1 = f2bf(acc2[2] * dn) | ((unsigned)f2bf(acc2[3] * dn) << 16);
    *(uint2*)(h2 + (size_t)node * 32 + c0) = make_uint2(p0, p1);
}

// Layer-2 aggregate: bf16 rows (32 ch), 4 threads/node -> 16 node-walks/wave.
__global__ __launch_bounds__(256) void agg2(const uint4* __restrict__ hs2,
                                            const float* __restrict__ dinv,
                                            const int* __restrict__ rp,
                                            const int* __restrict__ col,
                                            const float* __restrict__ bias,
                                            float* __restrict__ out, int N) {
    int t = blockIdx.x * blockDim.x + threadIdx.x;
    int node = t >> 2, q = t & 3;
    if (node >= N) return;
    float acc[8];
    uint4 u = hs2[(size_t)node * 4 + q];  // self-loop (pre-scaled)
    acc[0] = bflo(u.x); acc[1] = bfhi(u.x);
    acc[2] = bflo(u.y); acc[3] = bfhi(u.y);
    acc[4] = bflo(u.z); acc[5] = bfhi(u.z);
    acc[6] = bflo(u.w); acc[7] = bfhi(u.w);
    int e0 = rp[node], e1 = rp[node + 1];
    int e = e0;
#define ACC8(U)                               \
    acc[0] += bflo(U.x); acc[1] += bfhi(U.x); \
    acc[2] += bflo(U.y); acc[3] += bfhi(U.y); \
    acc[4] += bflo(U.z); acc[5] += bfhi(U.z); \
    acc[6] += bflo(U.w); acc[7] += bfhi(U.w);
    for (; e + 4 <= e1; e += 4) {
        int s0 = col[e], s1 = col[e + 1], s2 = col[e + 2], s3 = col[e + 3];
        uint4 u0 = hs2[(size_t)s0 * 4 + q];
        uint4 u1 = hs2[(size_t)s1 * 4 + q];
        uint4 u2 = hs2[(size_t)s2 * 4 + q];
        uint4 u3 = hs2[(size_t)s3 * 4 + q];
        ACC8(u0) ACC8(u1) ACC8(u2) ACC8(u3)
    }
    for (; e < e1; ++e) {
        uint4 uu = hs2[(size_t)col[e] * 4 + q];
        ACC8(uu)
    }
#undef ACC8
    float dn = dinv[node];
    const float4* bv = (const float4*)bias;
    float4 b0 = bv[q * 2], b1 = bv[q * 2 + 1];
    float4 r0, r1;
    r0.x = fmaf(acc[0], dn, b0.x);
    r0.y = fmaf(acc[1], dn, b0.y);
    r0.z = fmaf(acc[2], dn, b0.z);
    r0.w = fmaf(acc[3], dn, b0.w);
    r1.x = fmaf(acc[4], dn, b1.x);
    r1.y = fmaf(acc[5], dn, b1.y);
    r1.z = fmaf(acc[6], dn, b1.z);
    r1.w = fmaf(acc[7], dn, b1.w);
    float4* ov = (float4*)(out + (size_t)node * 32 + q * 8);
    ov[0] = r0;
    ov[1] = r1;
}

extern "C" void kernel_launch(void* const* d_in, const int* in_sizes, int n_in,
                              void* d_out, int out_size, void* d_ws, size_t ws_size,
                              hipStream_t stream) {
    const float* x = (const float*)d_in[0];
    const int* ei = (const int*)d_in[1];  // int64 in reference -> int32 from harness
    const float* W1 = (const float*)d_in[3];
    const float* b1 = (const float*)d_in[4];
    const float* W2 = (const float*)d_in[5];
    const float* b2 = (const float*)d_in[6];

    constexpr int CIN = 64, CHID = 64;
    const int N = in_sizes[0] / CIN;
    const int E = in_sizes[1] / 2;
    const int* src = ei;
    const int* dst = ei + E;
    const int NB = (N + 255) >> 8;

    char* p = (char*)d_ws;
    auto carve = [&](size_t bytes) -> void* {
        void* q = (void*)p;
        p += (bytes + 255) & ~(size_t)255;
        return q;
    };
    int* bucketCursor = (int*)carve((size_t)NB * 4);
    int* bucketBase = (int*)carve((size_t)(NB + 1) * 4);
    int* rp = (int*)carve((size_t)(N + 1) * 4);
    int* col = (int*)carve((size_t)E * 4);
    float* dinv = (float*)carve((size_t)N * 4);
    unsigned* staging = (unsigned*)carve((size_t)NB * CAP * 4);       // 12.8 MB
    unsigned short* h1 = (unsigned short*)carve((size_t)N * CHID * 2);  // bf16
    unsigned short* h2 = (unsigned short*)staging;  // staging dead after p2_csr

    hipMemsetAsync(bucketCursor, 0, (size_t)NB * 4, stream);
    p1_bin<<<(E + 4095) / 4096, 256, 0, stream>>>(src, dst, bucketCursor, staging, E, NB);
    scan_buckets<<<1, 512, 0, stream>>>(bucketCursor, bucketBase, rp, NB, N, E);
    p2_csr<<<NB, 256, 0, stream>>>(staging, bucketBase, rp, col, dinv, N);

    gemm1<<<(N + 127) / 128, 256, 0, stream>>>(x, W1, dinv, h1, N);
    agg1_gemm2<<<(N + 31) / 32, 256, 0, stream>>>((const uint4*)h1, dinv, rp, col, b1, W2, h2, N);
    agg2<<<((size_t)N * 4 + 255) / 256, 256, 0, stream>>>((const uint4*)h2, dinv, rp, col, b2,
                                                          (float*)d_out, N);
}